// Round 5
// baseline (264.120 us; speedup 1.0000x reference)
//
#include <hip/hip_runtime.h>
#include <hip/hip_bf16.h>

#define N_NODES 50000
#define N_EDGES 800000
#define N_RELS  32
#define D       64
#define TILE_M  256
#define NBKT    196                         // ceil(50000/256) dst buckets
#define SB      49                          // src sub-buckets (src>>10 in 0..48)
#define NKEY    (N_RELS * SB)               // 1568 composite (rel, srcbkt) keys
#define KPT     7                           // keys/thread in kB scan (256*7 >= 1568)
#define EPB     2048                        // edges per block in kA/kC
#define NEBLK   ((N_EDGES + EPB - 1) / EPB) // 391

typedef _Float16 half8 __attribute__((ext_vector_type(8)));
typedef float    f32x4 __attribute__((ext_vector_type(4)));

// ---------------- workspace layout (bytes) ----------------
#define OFF_BKTHIST 0u          // 196 int
#define OFF_KEYHIST 784u        // 1568 int   (memset [0,7056))
#define OFF_KEYCUR  7056u       // 1568 int
#define OFF_BKTCUR  13328u      // 196 int
#define OFF_ROFF    14112u      // 33 int
#define OFF_TB      14248u      // 33 int
#define OFF_BKTOFF  14384u      // 197 int
#define OFF_KEYOFF  15184u      // 1569 int
#define OFF_DSTOFF  21462u      // pad -> 21472; 50001 int
#define OFF_DSTOFF_A 21472u
#define OFF_RELSRC  221480u     // pad -> 221488; 800000 int
#define OFF_RELSRC_A 221488u
#define OFF_CSRY    3421488u    // 800000 int
#define OFF_WT      6621488u    // 32*64*64 fp16 (16B aligned)
#define OFF_Y       6883632u    // 800000*64 fp16 (bucketed[] aliases head)
#define WS_REQ      109283632u

// ---------------- fallback: atomic scatter path ----------------
__global__ __launch_bounds__(256) void rgcn_edge_atomic(
    const float* __restrict__ feat, const float* __restrict__ weight,
    const int* __restrict__ src, const int* __restrict__ dst,
    const int* __restrict__ et, float* __restrict__ out, int nquads)
{
    const int tid  = blockIdx.x * blockDim.x + threadIdx.x;
    const int wave = tid >> 6, lane = tid & 63;
    const int grp = lane >> 4, lg = lane & 15;
    const int wave_stride = (gridDim.x * blockDim.x) >> 6;
    for (int q = wave; q < nquads; q += wave_stride) {
        const int e = q * 4 + grp;
        const int s = src[e], d = dst[e], r = et[e];
        const float* w = weight + (size_t)r * D * D + lg * 4;
        float ax = 0.f, ay = 0.f, az = 0.f, aw = 0.f;
        #pragma unroll
        for (int i4 = 0; i4 < D / 4; ++i4) {
            const float4 f  = *reinterpret_cast<const float4*>(feat + (size_t)s * D + i4 * 4);
            const float4 w0 = *reinterpret_cast<const float4*>(w + (i4 * 4 + 0) * D);
            const float4 w1 = *reinterpret_cast<const float4*>(w + (i4 * 4 + 1) * D);
            const float4 w2 = *reinterpret_cast<const float4*>(w + (i4 * 4 + 2) * D);
            const float4 w3 = *reinterpret_cast<const float4*>(w + (i4 * 4 + 3) * D);
            ax += f.x*w0.x; ay += f.x*w0.y; az += f.x*w0.z; aw += f.x*w0.w;
            ax += f.y*w1.x; ay += f.y*w1.y; az += f.y*w1.z; aw += f.y*w1.w;
            ax += f.z*w2.x; ay += f.z*w2.y; az += f.z*w2.z; aw += f.z*w2.w;
            ax += f.w*w3.x; ay += f.w*w3.y; az += f.w*w3.z; aw += f.w*w3.w;
        }
        float* orow = out + (size_t)d * D + lg * 4;
        atomicAdd(orow + 0, ax); atomicAdd(orow + 1, ay);
        atomicAdd(orow + 2, az); atomicAdd(orow + 3, aw);
    }
}

// ---------------- K0: W -> W^T fp16 (wT[r][o][k]) ----------------
__global__ __launch_bounds__(256) void k0_wt(const float* __restrict__ w,
                                             _Float16* __restrict__ wT)
{
    const int r = blockIdx.x, t = threadIdx.x;
    #pragma unroll
    for (int i = 0; i < 16; ++i) {
        int oidx = i * 256 + t;
        int o = oidx >> 6, k = oidx & 63;
        wT[(size_t)r * 4096 + oidx] = (_Float16)w[(size_t)r * 4096 + k * 64 + o];
    }
}

// ---------------- kA: LDS-aggregated (rel,srcbkt)-key + dst-bucket hists ----
__global__ __launch_bounds__(256) void kA_hist(const int* __restrict__ et,
                                               const int* __restrict__ src,
                                               const int* __restrict__ dst,
                                               int* __restrict__ keyhist,
                                               int* __restrict__ bkthist)
{
    __shared__ int lk[NKEY];
    __shared__ int lb[NBKT];
    const int t = threadIdx.x;
    for (int k = t; k < NKEY; k += 256) lk[k] = 0;
    if (t < NBKT) lb[t] = 0;
    __syncthreads();
    const int base = blockIdx.x * EPB + t * 8;
    #pragma unroll
    for (int i = 0; i < 8; ++i) {
        int e = base + i;
        if (e < N_EDGES) {
            atomicAdd(&lk[et[e] * SB + (src[e] >> 10)], 1);
            atomicAdd(&lb[dst[e] >> 8], 1);
        }
    }
    __syncthreads();
    for (int k = t; k < NKEY; k += 256)
        if (lk[k]) atomicAdd(&keyhist[k], lk[k]);
    if (t < NBKT && lb[t]) atomicAdd(&bkthist[t], lb[t]);
}

// ---------------- kB: parallel scans (keys, rel offsets, tiles, buckets) ----
__global__ __launch_bounds__(256) void kB_scan(const int* __restrict__ keyhist,
                                               const int* __restrict__ bkthist,
                                               int* __restrict__ keyoff,
                                               int* __restrict__ keycur,
                                               int* __restrict__ roff,
                                               int* __restrict__ tb,
                                               int* __restrict__ bktoff,
                                               int* __restrict__ bktcur,
                                               int* __restrict__ dst_off)
{
    __shared__ int s[256];
    __shared__ int koff[NKEY + 1];
    const int t = threadIdx.x;
    // --- key scan (1568) : 7 keys per thread + 256-wide ladder ---
    int loc[KPT]; int run = 0;
    #pragma unroll
    for (int i = 0; i < KPT; ++i) {
        int k = t * KPT + i;
        int v = (k < NKEY) ? keyhist[k] : 0;
        loc[i] = run; run += v;
    }
    s[t] = run; __syncthreads();
    #pragma unroll
    for (int off = 1; off < 256; off <<= 1) {
        int u = (t >= off) ? s[t - off] : 0;
        __syncthreads(); s[t] += u; __syncthreads();
    }
    int base = (t > 0) ? s[t - 1] : 0;
    #pragma unroll
    for (int i = 0; i < KPT; ++i) {
        int k = t * KPT + i;
        if (k < NKEY) {
            int ex = base + loc[i];
            koff[k] = ex; keyoff[k] = ex; keycur[k] = ex;
        }
    }
    if (t == 0) {
        koff[NKEY] = N_EDGES; keyoff[NKEY] = N_EDGES;
        dst_off[N_NODES] = N_EDGES;
    }
    __syncthreads();
    // --- relation offsets + tile table (from key boundaries) ---
    int cnt = 0;
    if (t < N_RELS) {
        roff[t] = koff[t * SB];
        cnt = koff[(t + 1) * SB] - koff[t * SB];
    }
    if (t == 0) roff[N_RELS] = N_EDGES;
    int w = (cnt + TILE_M - 1) / TILE_M;
    s[t] = (t < N_RELS) ? w : 0; __syncthreads();
    #pragma unroll
    for (int off = 1; off < 32; off <<= 1) {
        int u = (t >= off && t < N_RELS) ? s[t - off] : 0;
        __syncthreads(); s[t] += u; __syncthreads();
    }
    if (t < N_RELS) tb[t] = s[t] - w;
    if (t == N_RELS - 1) tb[N_RELS] = s[t];
    __syncthreads();
    // --- dst-bucket scan (196) ---
    int v2 = (t < NBKT) ? bkthist[t] : 0;
    s[t] = v2; __syncthreads();
    #pragma unroll
    for (int off = 1; off < 256; off <<= 1) {
        int u = (t >= off) ? s[t - off] : 0;
        __syncthreads(); s[t] += u; __syncthreads();
    }
    if (t < NBKT) { int ex = s[t] - v2; bktoff[t] = ex; bktcur[t] = ex; }
    if (t == NBKT - 1) bktoff[NBKT] = s[t];
}

// ---------------- kC: (rel,srcbkt)-scatter + dst-bucket scatter -------------
__global__ __launch_bounds__(256) void kC_scatter(const int* __restrict__ src,
                                                  const int* __restrict__ dst,
                                                  const int* __restrict__ et,
                                                  int* __restrict__ keycur,
                                                  int* __restrict__ bktcur,
                                                  int* __restrict__ relsrc,
                                                  int* __restrict__ bucketed)
{
    __shared__ int lk[NKEY],  lkbase[NKEY];
    __shared__ int lb[NBKT],  lbase2[NBKT];
    const int t = threadIdx.x;
    for (int k = t; k < NKEY; k += 256) lk[k] = 0;
    if (t < NBKT) lb[t] = 0;
    __syncthreads();
    const int base = blockIdx.x * EPB + t * 8;
    int key_[8], b_[8], s_[8], d_[8], sl[8], sl2[8];
    #pragma unroll
    for (int i = 0; i < 8; ++i) {
        int e = base + i;
        if (e < N_EDGES) {
            s_[i] = src[e]; d_[i] = dst[e];
            key_[i] = et[e] * SB + (s_[i] >> 10);
            b_[i] = d_[i] >> 8;
            sl[i]  = atomicAdd(&lk[key_[i]], 1);
            sl2[i] = atomicAdd(&lb[b_[i]], 1);
        }
    }
    __syncthreads();
    for (int k = t; k < NKEY; k += 256)
        if (lk[k]) lkbase[k] = atomicAdd(&keycur[k], lk[k]);
    if (t < NBKT && lb[t]) lbase2[t] = atomicAdd(&bktcur[t], lb[t]);
    __syncthreads();
    #pragma unroll
    for (int i = 0; i < 8; ++i) {
        int e = base + i;
        if (e < N_EDGES) {
            int j = lkbase[key_[i]] + sl[i];
            relsrc[j] = s_[i];
            bucketed[lbase2[b_[i]] + sl2[i]] = ((d_[i] & 255) << 20) | j;
        }
    }
}

// ---------------- kD: per-bucket counting sort -> dst_off + csr_y -----------
__global__ __launch_bounds__(256) void kD_csr(const int* __restrict__ bucketed,
                                              const int* __restrict__ bktoff,
                                              int* __restrict__ csr_y,
                                              int* __restrict__ dst_off)
{
    __shared__ int hist[256];
    __shared__ int s[256];
    const int b = blockIdx.x, t = threadIdx.x;
    const int lo = bktoff[b], hi = bktoff[b + 1];
    hist[t] = 0; __syncthreads();
    for (int p = lo + t; p < hi; p += 256)
        atomicAdd(&hist[bucketed[p] >> 20], 1);
    __syncthreads();
    int v = hist[t];
    s[t] = v; __syncthreads();
    #pragma unroll
    for (int off = 1; off < 256; off <<= 1) {
        int u = (t >= off) ? s[t - off] : 0;
        __syncthreads(); s[t] += u; __syncthreads();
    }
    int ex = lo + s[t] - v;
    int n = b * 256 + t;
    if (n < N_NODES) dst_off[n] = ex;
    hist[t] = ex;
    __syncthreads();
    for (int p = lo + t; p < hi; p += 256) {
        int key = bucketed[p];
        int pos = atomicAdd(&hist[key >> 20], 1);
        csr_y[pos] = key & 0xFFFFF;
    }
}

// ---------------- K4: per-relation GEMM via MFMA -> Y fp16 (nt stores) ------
__global__ __launch_bounds__(256) void k4_gemm(const float* __restrict__ feat,
                                               const _Float16* __restrict__ wT,
                                               const int* __restrict__ relsrc,
                                               const int* __restrict__ roff,
                                               const int* __restrict__ tb,
                                               _Float16* __restrict__ Y)
{
    __shared__ _Float16 aT[TILE_M * 64];   // XOR-swizzled [row][k]
    __shared__ _Float16 wL[64 * 64];       // XOR-swizzled [out][k]
    const int b = blockIdx.x, t = threadIdx.x;

    int r = -1, ti = 0, t0 = 0;
    #pragma unroll
    for (int q = 0; q < N_RELS; ++q) {
        int t1 = tb[q + 1];
        if (b >= t0 && b < t1) { r = q; ti = b - t0; }
        t0 = t1;
    }
    if (r < 0) return;
    const int segstart = roff[r], segend = roff[r + 1];
    const int rowbase = segstart + ti * TILE_M;

    {
        const _Float16* wsrc = wT + (size_t)r * 4096;
        #pragma unroll
        for (int it = 0; it < 2; ++it) {
            int L8 = it * 256 + t;
            int o = L8 >> 3, kcol = (L8 & 7) * 8;
            int baddr = (o * 128 + kcol * 2) ^ ((o & 7) << 4);
            *reinterpret_cast<half8*>(reinterpret_cast<char*>(wL) + baddr) =
                *reinterpret_cast<const half8*>(wsrc + L8 * 8);
        }
    }
    {
        const int j = rowbase + t;
        const int sidx = (j < segend) ? relsrc[j] : 0;
        const float4* frow = reinterpret_cast<const float4*>(feat + (size_t)sidx * 64);
        #pragma unroll
        for (int c = 0; c < 4; ++c) {
            float4 f0 = frow[c*4+0], f1 = frow[c*4+1], f2 = frow[c*4+2], f3 = frow[c*4+3];
            half8 h0, h1;
            h0[0]=(_Float16)f0.x; h0[1]=(_Float16)f0.y; h0[2]=(_Float16)f0.z; h0[3]=(_Float16)f0.w;
            h0[4]=(_Float16)f1.x; h0[5]=(_Float16)f1.y; h0[6]=(_Float16)f1.z; h0[7]=(_Float16)f1.w;
            h1[0]=(_Float16)f2.x; h1[1]=(_Float16)f2.y; h1[2]=(_Float16)f2.z; h1[3]=(_Float16)f2.w;
            h1[4]=(_Float16)f3.x; h1[5]=(_Float16)f3.y; h1[6]=(_Float16)f3.z; h1[7]=(_Float16)f3.w;
            int base = t * 128 + c * 32;
            int a0 = (base)      ^ ((t & 7) << 4);
            int a1 = (base + 16) ^ ((t & 7) << 4);
            *reinterpret_cast<half8*>(reinterpret_cast<char*>(aT) + a0) = h0;
            *reinterpret_cast<half8*>(reinterpret_cast<char*>(aT) + a1) = h1;
        }
    }
    __syncthreads();

    const int wid = t >> 6, l = t & 63;
    const int lrow = l & 15, lkb = l >> 4;
    f32x4 acc[4][4] = {};
    #pragma unroll
    for (int ks = 0; ks < 2; ++ks) {
        half8 af[4], bfr[4];
        #pragma unroll
        for (int rt = 0; rt < 4; ++rt) {
            int row = wid * 64 + rt * 16 + lrow;
            int baddr = (row * 128 + ks * 64 + lkb * 16) ^ ((row & 7) << 4);
            af[rt] = *reinterpret_cast<const half8*>(reinterpret_cast<const char*>(aT) + baddr);
        }
        #pragma unroll
        for (int ct = 0; ct < 4; ++ct) {
            int n = ct * 16 + lrow;
            int baddr = (n * 128 + ks * 64 + lkb * 16) ^ ((n & 7) << 4);
            bfr[ct] = *reinterpret_cast<const half8*>(reinterpret_cast<const char*>(wL) + baddr);
        }
        #pragma unroll
        for (int rt = 0; rt < 4; ++rt)
            #pragma unroll
            for (int ct = 0; ct < 4; ++ct)
                acc[rt][ct] = __builtin_amdgcn_mfma_f32_16x16x32_f16(af[rt], bfr[ct], acc[rt][ct], 0, 0, 0);
    }
    #pragma unroll
    for (int rt = 0; rt < 4; ++rt) {
        int rowg = rowbase + wid * 64 + rt * 16 + (l >> 4) * 4;
        #pragma unroll
        for (int ct = 0; ct < 4; ++ct) {
            int col = ct * 16 + lrow;
            #pragma unroll
            for (int reg = 0; reg < 4; ++reg) {
                int row = rowg + reg;
                if (row < segend)
                    __builtin_nontemporal_store((_Float16)acc[rt][ct][reg],
                                                &Y[(size_t)row * 64 + col]);
            }
        }
    }
}

// ---------------- K5: dst-CSR gather reduce ----------------
__global__ __launch_bounds__(256) void k5_reduce(const _Float16* __restrict__ Y,
                                                 const int* __restrict__ csr_y,
                                                 const int* __restrict__ dst_off,
                                                 float* __restrict__ out)
{
    const int wid = threadIdx.x >> 6, l = threadIdx.x & 63;
    const int n = blockIdx.x * 4 + wid;
    if (n >= N_NODES) return;
    const int p0 = dst_off[n], p1 = dst_off[n + 1];
    float acc = 0.f;
    int p = p0;
    for (; p + 4 <= p1; p += 4) {
        int ja = csr_y[p], jb = csr_y[p+1], jc = csr_y[p+2], jd = csr_y[p+3];
        acc += (float)Y[(size_t)ja * 64 + l] + (float)Y[(size_t)jb * 64 + l]
             + (float)Y[(size_t)jc * 64 + l] + (float)Y[(size_t)jd * 64 + l];
    }
    for (; p < p1; ++p)
        acc += (float)Y[(size_t)csr_y[p] * 64 + l];
    out[(size_t)n * 64 + l] = acc;
}

extern "C" void kernel_launch(void* const* d_in, const int* in_sizes, int n_in,
                              void* d_out, int out_size, void* d_ws, size_t ws_size,
                              hipStream_t stream) {
    const float* feat   = (const float*)d_in[0];
    const float* weight = (const float*)d_in[1];
    const int*   src    = (const int*)d_in[2];
    const int*   dst    = (const int*)d_in[3];
    const int*   et     = (const int*)d_in[4];
    float*       out    = (float*)d_out;

    if (ws_size < (size_t)WS_REQ) {
        hipMemsetAsync(d_out, 0, (size_t)out_size * sizeof(float), stream);
        hipLaunchKernelGGL(rgcn_edge_atomic, dim3(4096), dim3(256), 0, stream,
                           feat, weight, src, dst, et, out, N_EDGES / 4);
        return;
    }

    char* ws = (char*)d_ws;
    int*       bkthist  = (int*)(ws + OFF_BKTHIST);
    int*       keyhist  = (int*)(ws + OFF_KEYHIST);
    int*       keycur   = (int*)(ws + OFF_KEYCUR);
    int*       bktcur   = (int*)(ws + OFF_BKTCUR);
    int*       roff     = (int*)(ws + OFF_ROFF);
    int*       tb       = (int*)(ws + OFF_TB);
    int*       bktoff   = (int*)(ws + OFF_BKTOFF);
    int*       keyoff   = (int*)(ws + OFF_KEYOFF);
    int*       dst_off  = (int*)(ws + OFF_DSTOFF_A);
    int*       relsrc   = (int*)(ws + OFF_RELSRC_A);
    int*       csr_y    = (int*)(ws + OFF_CSRY);
    _Float16*  wT       = (_Float16*)(ws + OFF_WT);
    _Float16*  Y        = (_Float16*)(ws + OFF_Y);
    int*       bucketed = (int*)(ws + OFF_Y);   // aliases Y head; dead before k4

    hipMemsetAsync(ws, 0, 7056, stream);        // bkthist + keyhist

    hipLaunchKernelGGL(k0_wt,      dim3(N_RELS), dim3(256), 0, stream, weight, wT);
    hipLaunchKernelGGL(kA_hist,    dim3(NEBLK),  dim3(256), 0, stream, et, src, dst, keyhist, bkthist);
    hipLaunchKernelGGL(kB_scan,    dim3(1),      dim3(256), 0, stream, keyhist, bkthist, keyoff, keycur, roff, tb, bktoff, bktcur, dst_off);
    hipLaunchKernelGGL(kC_scatter, dim3(NEBLK),  dim3(256), 0, stream, src, dst, et, keycur, bktcur, relsrc, bucketed);
    hipLaunchKernelGGL(kD_csr,     dim3(NBKT),   dim3(256), 0, stream, bucketed, bktoff, csr_y, dst_off);
    const int max_tiles = N_EDGES / TILE_M + N_RELS;
    hipLaunchKernelGGL(k4_gemm,    dim3(max_tiles),         dim3(256), 0, stream, feat, wT, relsrc, roff, tb, Y);
    hipLaunchKernelGGL(k5_reduce,  dim3((N_NODES + 3) / 4), dim3(256), 0, stream, Y, csr_y, dst_off, out);
}

// Round 6
// 135.215 us; speedup vs baseline: 1.9533x; 1.9533x over previous
//
#include <hip/hip_runtime.h>
#include <hip/hip_bf16.h>

#define N_NODES 50000
#define N_EDGES 800000
#define N_RELS  32
#define D       64
#define TILE_M  256
#define NBKT    196                         // ceil(50000/256)
#define EPB     2048                        // edges per block in kA/kC
#define NEBLK   ((N_EDGES + EPB - 1) / EPB) // 391

typedef _Float16 half8 __attribute__((ext_vector_type(8)));
typedef float    f32x4 __attribute__((ext_vector_type(4)));

// ---------------- workspace layout (bytes) ----------------
#define OFF_RELHIST 0u          // 32 int
#define OFF_BKTHIST 128u        // 196 int   (memset [0,912))
#define OFF_RELCUR  1024u       // 32 int
#define OFF_BKTCUR  1152u       // 196 int
#define OFF_ROFF    1936u       // 33 int
#define OFF_TB      2080u       // 33 int
#define OFF_BKTOFF  2224u       // 197 int
#define OFF_DSTOFF  3072u       // 50001 int
#define OFF_RELSRC  203776u     // 800000 int
#define OFF_CSRY    3403776u    // 800000 int
#define OFF_WT      6603776u    // 32*64*64 fp16
#define OFF_FEATH   6865920u    // 50000*64 fp16 = 6.4 MB   (full layout only)
#define OFF_Y_FULL  13265920u   // 800000*64 fp16
#define OFF_Y_BASE  6865920u    // Y location when featH doesn't fit
#define WS_FULL     115665920u
#define WS_BASE     109265920u

// ---------------- fallback: atomic scatter path ----------------
__global__ __launch_bounds__(256) void rgcn_edge_atomic(
    const float* __restrict__ feat, const float* __restrict__ weight,
    const int* __restrict__ src, const int* __restrict__ dst,
    const int* __restrict__ et, float* __restrict__ out, int nquads)
{
    const int tid  = blockIdx.x * blockDim.x + threadIdx.x;
    const int wave = tid >> 6, lane = tid & 63;
    const int grp = lane >> 4, lg = lane & 15;
    const int wave_stride = (gridDim.x * blockDim.x) >> 6;
    for (int q = wave; q < nquads; q += wave_stride) {
        const int e = q * 4 + grp;
        const int s = src[e], d = dst[e], r = et[e];
        const float* w = weight + (size_t)r * D * D + lg * 4;
        float ax = 0.f, ay = 0.f, az = 0.f, aw = 0.f;
        #pragma unroll
        for (int i4 = 0; i4 < D / 4; ++i4) {
            const float4 f  = *reinterpret_cast<const float4*>(feat + (size_t)s * D + i4 * 4);
            const float4 w0 = *reinterpret_cast<const float4*>(w + (i4 * 4 + 0) * D);
            const float4 w1 = *reinterpret_cast<const float4*>(w + (i4 * 4 + 1) * D);
            const float4 w2 = *reinterpret_cast<const float4*>(w + (i4 * 4 + 2) * D);
            const float4 w3 = *reinterpret_cast<const float4*>(w + (i4 * 4 + 3) * D);
            ax += f.x*w0.x; ay += f.x*w0.y; az += f.x*w0.z; aw += f.x*w0.w;
            ax += f.y*w1.x; ay += f.y*w1.y; az += f.y*w1.z; aw += f.y*w1.w;
            ax += f.z*w2.x; ay += f.z*w2.y; az += f.z*w2.z; aw += f.z*w2.w;
            ax += f.w*w3.x; ay += f.w*w3.y; az += f.w*w3.z; aw += f.w*w3.w;
        }
        float* orow = out + (size_t)d * D + lg * 4;
        atomicAdd(orow + 0, ax); atomicAdd(orow + 1, ay);
        atomicAdd(orow + 2, az); atomicAdd(orow + 3, aw);
    }
}

// ---------------- K0: W -> W^T fp16 (wT[r][o][k]) ----------------
__global__ __launch_bounds__(256) void k0_wt(const float* __restrict__ w,
                                             _Float16* __restrict__ wT)
{
    const int r = blockIdx.x, t = threadIdx.x;
    #pragma unroll
    for (int i = 0; i < 16; ++i) {
        int oidx = i * 256 + t;
        int o = oidx >> 6, k = oidx & 63;
        wT[(size_t)r * 4096 + oidx] = (_Float16)w[(size_t)r * 4096 + k * 64 + o];
    }
}

// ---------------- kF: feat -> fp16 (streaming, coalesced) ----------------
__global__ __launch_bounds__(256) void kF_feath(const float* __restrict__ feat,
                                                _Float16* __restrict__ featH)
{
    const int base = (blockIdx.x * 256 + threadIdx.x) * 8;
    if (base >= N_NODES * D) return;
    float4 f0 = *reinterpret_cast<const float4*>(feat + base);
    float4 f1 = *reinterpret_cast<const float4*>(feat + base + 4);
    half8 h;
    h[0]=(_Float16)f0.x; h[1]=(_Float16)f0.y; h[2]=(_Float16)f0.z; h[3]=(_Float16)f0.w;
    h[4]=(_Float16)f1.x; h[5]=(_Float16)f1.y; h[6]=(_Float16)f1.z; h[7]=(_Float16)f1.w;
    *reinterpret_cast<half8*>(featH + base) = h;
}

// ---------------- kA: LDS-aggregated rel + bucket histograms ----------------
__global__ __launch_bounds__(256) void kA_hist(const int* __restrict__ et,
                                               const int* __restrict__ dst,
                                               int* __restrict__ relhist,
                                               int* __restrict__ bkthist)
{
    __shared__ int lh[N_RELS];
    __shared__ int lb[NBKT];
    const int t = threadIdx.x;
    if (t < N_RELS) lh[t] = 0;
    if (t < NBKT)   lb[t] = 0;
    __syncthreads();
    const int base = blockIdx.x * EPB + t * 8;
    #pragma unroll
    for (int i = 0; i < 8; ++i) {
        int e = base + i;
        if (e < N_EDGES) {
            atomicAdd(&lh[et[e]], 1);
            atomicAdd(&lb[dst[e] >> 8], 1);
        }
    }
    __syncthreads();
    if (t < N_RELS && lh[t]) atomicAdd(&relhist[t], lh[t]);
    if (t < NBKT   && lb[t]) atomicAdd(&bkthist[t], lb[t]);
}

// ---------------- kB: parallel scans (rel offsets, tile table, bucket offs) -
__global__ __launch_bounds__(256) void kB_scan(const int* __restrict__ relhist,
                                               const int* __restrict__ bkthist,
                                               int* __restrict__ roff,
                                               int* __restrict__ relcur,
                                               int* __restrict__ tb,
                                               int* __restrict__ bktoff,
                                               int* __restrict__ bktcur,
                                               int* __restrict__ dst_off)
{
    __shared__ int s[256];
    const int t = threadIdx.x;
    int v = (t < N_RELS) ? relhist[t] : 0;
    s[t] = v; __syncthreads();
    #pragma unroll
    for (int off = 1; off < 32; off <<= 1) {
        int u = (t >= off && t < N_RELS) ? s[t - off] : 0;
        __syncthreads(); s[t] += u; __syncthreads();
    }
    if (t < N_RELS) { int ex = s[t] - v; roff[t] = ex; relcur[t] = ex; }
    if (t == N_RELS - 1) roff[N_RELS] = s[t];
    __syncthreads();
    int w = (v + TILE_M - 1) / TILE_M;
    s[t] = (t < N_RELS) ? w : 0; __syncthreads();
    #pragma unroll
    for (int off = 1; off < 32; off <<= 1) {
        int u = (t >= off && t < N_RELS) ? s[t - off] : 0;
        __syncthreads(); s[t] += u; __syncthreads();
    }
    if (t < N_RELS) tb[t] = s[t] - w;
    if (t == N_RELS - 1) tb[N_RELS] = s[t];
    __syncthreads();
    int v2 = (t < NBKT) ? bkthist[t] : 0;
    s[t] = v2; __syncthreads();
    #pragma unroll
    for (int off = 1; off < 256; off <<= 1) {
        int u = (t >= off) ? s[t - off] : 0;
        __syncthreads(); s[t] += u; __syncthreads();
    }
    if (t < NBKT) { int ex = s[t] - v2; bktoff[t] = ex; bktcur[t] = ex; }
    if (t == NBKT - 1) bktoff[NBKT] = s[t];
    if (t == 0) dst_off[N_NODES] = N_EDGES;
}

// ---------------- kC: rel-scatter + dst-bucket scatter (LDS-aggregated) -----
__global__ __launch_bounds__(256) void kC_scatter(const int* __restrict__ src,
                                                  const int* __restrict__ dst,
                                                  const int* __restrict__ et,
                                                  int* __restrict__ relcur,
                                                  int* __restrict__ bktcur,
                                                  int* __restrict__ relsrc,
                                                  int* __restrict__ bucketed)
{
    __shared__ int lh[N_RELS],  lbase[N_RELS];
    __shared__ int lb[NBKT],    lbase2[NBKT];
    const int t = threadIdx.x;
    if (t < N_RELS) lh[t] = 0;
    if (t < NBKT)   lb[t] = 0;
    __syncthreads();
    const int base = blockIdx.x * EPB + t * 8;
    int r_[8], b_[8], s_[8], d_[8], sl[8], sl2[8];
    #pragma unroll
    for (int i = 0; i < 8; ++i) {
        int e = base + i;
        if (e < N_EDGES) {
            r_[i] = et[e]; s_[i] = src[e]; d_[i] = dst[e];
            b_[i] = d_[i] >> 8;
            sl[i]  = atomicAdd(&lh[r_[i]], 1);
            sl2[i] = atomicAdd(&lb[b_[i]], 1);
        }
    }
    __syncthreads();
    if (t < N_RELS && lh[t]) lbase[t]  = atomicAdd(&relcur[t], lh[t]);
    if (t < NBKT   && lb[t]) lbase2[t] = atomicAdd(&bktcur[t], lb[t]);
    __syncthreads();
    #pragma unroll
    for (int i = 0; i < 8; ++i) {
        int e = base + i;
        if (e < N_EDGES) {
            int j = lbase[r_[i]] + sl[i];
            relsrc[j] = s_[i];
            bucketed[lbase2[b_[i]] + sl2[i]] = ((d_[i] & 255) << 20) | j;
        }
    }
}

// ---------------- kD: per-bucket counting sort -> dst_off + csr_y -----------
__global__ __launch_bounds__(256) void kD_csr(const int* __restrict__ bucketed,
                                              const int* __restrict__ bktoff,
                                              int* __restrict__ csr_y,
                                              int* __restrict__ dst_off)
{
    __shared__ int hist[256];
    __shared__ int s[256];
    const int b = blockIdx.x, t = threadIdx.x;
    const int lo = bktoff[b], hi = bktoff[b + 1];
    hist[t] = 0; __syncthreads();
    for (int p = lo + t; p < hi; p += 256)
        atomicAdd(&hist[bucketed[p] >> 20], 1);
    __syncthreads();
    int v = hist[t];
    s[t] = v; __syncthreads();
    #pragma unroll
    for (int off = 1; off < 256; off <<= 1) {
        int u = (t >= off) ? s[t - off] : 0;
        __syncthreads(); s[t] += u; __syncthreads();
    }
    int ex = lo + s[t] - v;
    int n = b * 256 + t;
    if (n < N_NODES) dst_off[n] = ex;
    hist[t] = ex;
    __syncthreads();
    for (int p = lo + t; p < hi; p += 256) {
        int key = bucketed[p];
        int pos = atomicAdd(&hist[key >> 20], 1);
        csr_y[pos] = key & 0xFFFFF;
    }
}

// ---------------- K4: per-relation GEMM via MFMA -> Y fp16 ----------------
// USE_H: gather A rows from fp16 featH (half fetch volume) vs fp32 feat.
template <bool USE_H>
__global__ __launch_bounds__(256) void k4_gemm(const float* __restrict__ feat,
                                               const _Float16* __restrict__ featH,
                                               const _Float16* __restrict__ wT,
                                               const int* __restrict__ relsrc,
                                               const int* __restrict__ roff,
                                               const int* __restrict__ tb,
                                               _Float16* __restrict__ Y)
{
    __shared__ _Float16 aT[TILE_M * 64];   // XOR-swizzled [row][k]
    __shared__ _Float16 wL[64 * 64];       // XOR-swizzled [out][k]
    const int b = blockIdx.x, t = threadIdx.x;

    int r = -1, ti = 0, t0 = 0;
    #pragma unroll
    for (int q = 0; q < N_RELS; ++q) {
        int t1 = tb[q + 1];
        if (b >= t0 && b < t1) { r = q; ti = b - t0; }
        t0 = t1;
    }
    if (r < 0) return;
    const int segstart = roff[r], segend = roff[r + 1];
    const int rowbase = segstart + ti * TILE_M;

    {
        const _Float16* wsrc = wT + (size_t)r * 4096;
        #pragma unroll
        for (int it = 0; it < 2; ++it) {
            int L8 = it * 256 + t;
            int o = L8 >> 3, kcol = (L8 & 7) * 8;
            int baddr = (o * 128 + kcol * 2) ^ ((o & 7) << 4);
            *reinterpret_cast<half8*>(reinterpret_cast<char*>(wL) + baddr) =
                *reinterpret_cast<const half8*>(wsrc + L8 * 8);
        }
    }
    {
        const int j = rowbase + t;
        const int sidx = (j < segend) ? relsrc[j] : 0;
        if (USE_H) {
            const half8* hrow = reinterpret_cast<const half8*>(featH + (size_t)sidx * 64);
            #pragma unroll
            for (int c = 0; c < 4; ++c) {
                half8 h0 = hrow[c * 2 + 0];
                half8 h1 = hrow[c * 2 + 1];
                int base = t * 128 + c * 32;
                int a0 = (base)      ^ ((t & 7) << 4);
                int a1 = (base + 16) ^ ((t & 7) << 4);
                *reinterpret_cast<half8*>(reinterpret_cast<char*>(aT) + a0) = h0;
                *reinterpret_cast<half8*>(reinterpret_cast<char*>(aT) + a1) = h1;
            }
        } else {
            const float4* frow = reinterpret_cast<const float4*>(feat + (size_t)sidx * 64);
            #pragma unroll
            for (int c = 0; c < 4; ++c) {
                float4 f0 = frow[c*4+0], f1 = frow[c*4+1], f2 = frow[c*4+2], f3 = frow[c*4+3];
                half8 h0, h1;
                h0[0]=(_Float16)f0.x; h0[1]=(_Float16)f0.y; h0[2]=(_Float16)f0.z; h0[3]=(_Float16)f0.w;
                h0[4]=(_Float16)f1.x; h0[5]=(_Float16)f1.y; h0[6]=(_Float16)f1.z; h0[7]=(_Float16)f1.w;
                h1[0]=(_Float16)f2.x; h1[1]=(_Float16)f2.y; h1[2]=(_Float16)f2.z; h1[3]=(_Float16)f2.w;
                h1[4]=(_Float16)f3.x; h1[5]=(_Float16)f3.y; h1[6]=(_Float16)f3.z; h1[7]=(_Float16)f3.w;
                int base = t * 128 + c * 32;
                int a0 = (base)      ^ ((t & 7) << 4);
                int a1 = (base + 16) ^ ((t & 7) << 4);
                *reinterpret_cast<half8*>(reinterpret_cast<char*>(aT) + a0) = h0;
                *reinterpret_cast<half8*>(reinterpret_cast<char*>(aT) + a1) = h1;
            }
        }
    }
    __syncthreads();

    const int wid = t >> 6, l = t & 63;
    const int lrow = l & 15, lkb = l >> 4;
    f32x4 acc[4][4] = {};
    #pragma unroll
    for (int ks = 0; ks < 2; ++ks) {
        half8 af[4], bfr[4];
        #pragma unroll
        for (int rt = 0; rt < 4; ++rt) {
            int row = wid * 64 + rt * 16 + lrow;
            int baddr = (row * 128 + ks * 64 + lkb * 16) ^ ((row & 7) << 4);
            af[rt] = *reinterpret_cast<const half8*>(reinterpret_cast<const char*>(aT) + baddr);
        }
        #pragma unroll
        for (int ct = 0; ct < 4; ++ct) {
            int n = ct * 16 + lrow;
            int baddr = (n * 128 + ks * 64 + lkb * 16) ^ ((n & 7) << 4);
            bfr[ct] = *reinterpret_cast<const half8*>(reinterpret_cast<const char*>(wL) + baddr);
        }
        #pragma unroll
        for (int rt = 0; rt < 4; ++rt)
            #pragma unroll
            for (int ct = 0; ct < 4; ++ct)
                acc[rt][ct] = __builtin_amdgcn_mfma_f32_16x16x32_f16(af[rt], bfr[ct], acc[rt][ct], 0, 0, 0);
    }
    #pragma unroll
    for (int rt = 0; rt < 4; ++rt) {
        int rowg = rowbase + wid * 64 + rt * 16 + (l >> 4) * 4;
        #pragma unroll
        for (int ct = 0; ct < 4; ++ct) {
            int col = ct * 16 + lrow;
            #pragma unroll
            for (int reg = 0; reg < 4; ++reg) {
                int row = rowg + reg;
                if (row < segend)
                    Y[(size_t)row * 64 + col] = (_Float16)acc[rt][ct][reg];
            }
        }
    }
}

// ---------------- K5: dst-CSR gather reduce ----------------
__global__ __launch_bounds__(256) void k5_reduce(const _Float16* __restrict__ Y,
                                                 const int* __restrict__ csr_y,
                                                 const int* __restrict__ dst_off,
                                                 float* __restrict__ out)
{
    const int wid = threadIdx.x >> 6, l = threadIdx.x & 63;
    const int n = blockIdx.x * 4 + wid;
    if (n >= N_NODES) return;
    const int p0 = dst_off[n], p1 = dst_off[n + 1];
    float acc = 0.f;
    int p = p0;
    for (; p + 4 <= p1; p += 4) {
        int ja = csr_y[p], jb = csr_y[p+1], jc = csr_y[p+2], jd = csr_y[p+3];
        acc += (float)Y[(size_t)ja * 64 + l] + (float)Y[(size_t)jb * 64 + l]
             + (float)Y[(size_t)jc * 64 + l] + (float)Y[(size_t)jd * 64 + l];
    }
    for (; p < p1; ++p)
        acc += (float)Y[(size_t)csr_y[p] * 64 + l];
    out[(size_t)n * 64 + l] = acc;
}

extern "C" void kernel_launch(void* const* d_in, const int* in_sizes, int n_in,
                              void* d_out, int out_size, void* d_ws, size_t ws_size,
                              hipStream_t stream) {
    const float* feat   = (const float*)d_in[0];
    const float* weight = (const float*)d_in[1];
    const int*   src    = (const int*)d_in[2];
    const int*   dst    = (const int*)d_in[3];
    const int*   et     = (const int*)d_in[4];
    float*       out    = (float*)d_out;

    if (ws_size < (size_t)WS_BASE) {
        hipMemsetAsync(d_out, 0, (size_t)out_size * sizeof(float), stream);
        hipLaunchKernelGGL(rgcn_edge_atomic, dim3(4096), dim3(256), 0, stream,
                           feat, weight, src, dst, et, out, N_EDGES / 4);
        return;
    }
    const bool use_h = (ws_size >= (size_t)WS_FULL);

    char* ws = (char*)d_ws;
    int*       relhist  = (int*)(ws + OFF_RELHIST);
    int*       bkthist  = (int*)(ws + OFF_BKTHIST);
    int*       relcur   = (int*)(ws + OFF_RELCUR);
    int*       bktcur   = (int*)(ws + OFF_BKTCUR);
    int*       roff     = (int*)(ws + OFF_ROFF);
    int*       tb       = (int*)(ws + OFF_TB);
    int*       bktoff   = (int*)(ws + OFF_BKTOFF);
    int*       dst_off  = (int*)(ws + OFF_DSTOFF);
    int*       relsrc   = (int*)(ws + OFF_RELSRC);
    int*       csr_y    = (int*)(ws + OFF_CSRY);
    _Float16*  wT       = (_Float16*)(ws + OFF_WT);
    _Float16*  featH    = (_Float16*)(ws + OFF_FEATH);
    _Float16*  Y        = (_Float16*)(ws + (use_h ? OFF_Y_FULL : OFF_Y_BASE));
    int*       bucketed = (int*)Y;              // aliases Y head; dead before k4

    hipMemsetAsync(ws, 0, 912, stream);         // relhist + bkthist

    hipLaunchKernelGGL(k0_wt,      dim3(N_RELS), dim3(256), 0, stream, weight, wT);
    if (use_h)
        hipLaunchKernelGGL(kF_feath, dim3((N_NODES * D / 8 + 255) / 256), dim3(256), 0, stream, feat, featH);
    hipLaunchKernelGGL(kA_hist,    dim3(NEBLK),  dim3(256), 0, stream, et, dst, relhist, bkthist);
    hipLaunchKernelGGL(kB_scan,    dim3(1),      dim3(256), 0, stream, relhist, bkthist, roff, relcur, tb, bktoff, bktcur, dst_off);
    hipLaunchKernelGGL(kC_scatter, dim3(NEBLK),  dim3(256), 0, stream, src, dst, et, relcur, bktcur, relsrc, bucketed);
    hipLaunchKernelGGL(kD_csr,     dim3(NBKT),   dim3(256), 0, stream, bucketed, bktoff, csr_y, dst_off);
    const int max_tiles = N_EDGES / TILE_M + N_RELS;
    if (use_h)
        hipLaunchKernelGGL((k4_gemm<true>),  dim3(max_tiles), dim3(256), 0, stream, feat, featH, wT, relsrc, roff, tb, Y);
    else
        hipLaunchKernelGGL((k4_gemm<false>), dim3(max_tiles), dim3(256), 0, stream, feat, featH, wT, relsrc, roff, tb, Y);
    hipLaunchKernelGGL(k5_reduce,  dim3((N_NODES + 3) / 4), dim3(256), 0, stream, Y, csr_y, dst_off, out);
}

// Round 7
// 119.451 us; speedup vs baseline: 2.2111x; 1.1320x over previous
//
#include <hip/hip_runtime.h>
#include <hip/hip_bf16.h>

#define N_NODES 50000
#define N_EDGES 800000
#define N_RELS  32
#define D       64
#define TILE_M  128
#define NBKT    196                         // ceil(50000/256)
#define EPB     2048                        // edges per block in kA/kC
#define NEBLK   ((N_EDGES + EPB - 1) / EPB) // 391

typedef _Float16 half8 __attribute__((ext_vector_type(8)));
typedef float    f32x4 __attribute__((ext_vector_type(4)));

// ---------------- workspace layout (bytes) ----------------
#define OFF_RELHIST 0u          // 32 int
#define OFF_BKTHIST 128u        // 196 int   (memset [0,912))
#define OFF_RELCUR  1024u       // 32 int
#define OFF_BKTCUR  1152u       // 196 int
#define OFF_ROFF    1936u       // 33 int
#define OFF_TB      2080u       // 33 int
#define OFF_BKTOFF  2224u       // 197 int
#define OFF_DSTOFF  3072u       // 50001 int
#define OFF_RELSRC  203776u     // 800000 int
#define OFF_J2POS   3403776u    // 800000 int (edge j -> dst-CSR position)
#define OFF_WT      6603776u    // 32*64*64 fp16
#define OFF_FEATH   6865920u    // 50000*64 fp16 (full layout only)
#define OFF_Y_FULL  13265920u   // 800000*64 fp16, dst-ordered
#define OFF_Y_BASE  6865920u    // Y location when featH doesn't fit
#define WS_FULL     115665920u
#define WS_BASE     109265920u

// ---------------- fallback: atomic scatter path ----------------
__global__ __launch_bounds__(256) void rgcn_edge_atomic(
    const float* __restrict__ feat, const float* __restrict__ weight,
    const int* __restrict__ src, const int* __restrict__ dst,
    const int* __restrict__ et, float* __restrict__ out, int nquads)
{
    const int tid  = blockIdx.x * blockDim.x + threadIdx.x;
    const int wave = tid >> 6, lane = tid & 63;
    const int grp = lane >> 4, lg = lane & 15;
    const int wave_stride = (gridDim.x * blockDim.x) >> 6;
    for (int q = wave; q < nquads; q += wave_stride) {
        const int e = q * 4 + grp;
        const int s = src[e], d = dst[e], r = et[e];
        const float* w = weight + (size_t)r * D * D + lg * 4;
        float ax = 0.f, ay = 0.f, az = 0.f, aw = 0.f;
        #pragma unroll
        for (int i4 = 0; i4 < D / 4; ++i4) {
            const float4 f  = *reinterpret_cast<const float4*>(feat + (size_t)s * D + i4 * 4);
            const float4 w0 = *reinterpret_cast<const float4*>(w + (i4 * 4 + 0) * D);
            const float4 w1 = *reinterpret_cast<const float4*>(w + (i4 * 4 + 1) * D);
            const float4 w2 = *reinterpret_cast<const float4*>(w + (i4 * 4 + 2) * D);
            const float4 w3 = *reinterpret_cast<const float4*>(w + (i4 * 4 + 3) * D);
            ax += f.x*w0.x; ay += f.x*w0.y; az += f.x*w0.z; aw += f.x*w0.w;
            ax += f.y*w1.x; ay += f.y*w1.y; az += f.y*w1.z; aw += f.y*w1.w;
            ax += f.z*w2.x; ay += f.z*w2.y; az += f.z*w2.z; aw += f.z*w2.w;
            ax += f.w*w3.x; ay += f.w*w3.y; az += f.w*w3.z; aw += f.w*w3.w;
        }
        float* orow = out + (size_t)d * D + lg * 4;
        atomicAdd(orow + 0, ax); atomicAdd(orow + 1, ay);
        atomicAdd(orow + 2, az); atomicAdd(orow + 3, aw);
    }
}

// ---------------- kPre: W->W^T fp16  +  feat->fp16 (fused) ----------------
__global__ __launch_bounds__(256) void kPre(const float* __restrict__ w,
                                            _Float16* __restrict__ wT,
                                            const float* __restrict__ feat,
                                            _Float16* __restrict__ featH)
{
    const int t = threadIdx.x;
    if (blockIdx.x < N_RELS) {
        const int r = blockIdx.x;
        #pragma unroll
        for (int i = 0; i < 16; ++i) {
            int oidx = i * 256 + t;
            int o = oidx >> 6, k = oidx & 63;
            wT[(size_t)r * 4096 + oidx] = (_Float16)w[(size_t)r * 4096 + k * 64 + o];
        }
    } else {
        const int base = ((blockIdx.x - N_RELS) * 256 + t) * 8;
        if (base >= N_NODES * D) return;
        float4 f0 = *reinterpret_cast<const float4*>(feat + base);
        float4 f1 = *reinterpret_cast<const float4*>(feat + base + 4);
        half8 h;
        h[0]=(_Float16)f0.x; h[1]=(_Float16)f0.y; h[2]=(_Float16)f0.z; h[3]=(_Float16)f0.w;
        h[4]=(_Float16)f1.x; h[5]=(_Float16)f1.y; h[6]=(_Float16)f1.z; h[7]=(_Float16)f1.w;
        *reinterpret_cast<half8*>(featH + base) = h;
    }
}

// ---------------- kA: LDS-aggregated rel + bucket histograms ----------------
__global__ __launch_bounds__(256) void kA_hist(const int* __restrict__ et,
                                               const int* __restrict__ dst,
                                               int* __restrict__ relhist,
                                               int* __restrict__ bkthist)
{
    __shared__ int lh[N_RELS];
    __shared__ int lb[NBKT];
    const int t = threadIdx.x;
    if (t < N_RELS) lh[t] = 0;
    if (t < NBKT)   lb[t] = 0;
    __syncthreads();
    const int base = blockIdx.x * EPB + t * 8;
    #pragma unroll
    for (int i = 0; i < 8; ++i) {
        int e = base + i;
        if (e < N_EDGES) {
            atomicAdd(&lh[et[e]], 1);
            atomicAdd(&lb[dst[e] >> 8], 1);
        }
    }
    __syncthreads();
    if (t < N_RELS && lh[t]) atomicAdd(&relhist[t], lh[t]);
    if (t < NBKT   && lb[t]) atomicAdd(&bkthist[t], lb[t]);
}

// ---------------- kB: parallel scans (rel offsets, tile table, bucket offs) -
__global__ __launch_bounds__(256) void kB_scan(const int* __restrict__ relhist,
                                               const int* __restrict__ bkthist,
                                               int* __restrict__ roff,
                                               int* __restrict__ relcur,
                                               int* __restrict__ tb,
                                               int* __restrict__ bktoff,
                                               int* __restrict__ bktcur,
                                               int* __restrict__ dst_off)
{
    __shared__ int s[256];
    const int t = threadIdx.x;
    int v = (t < N_RELS) ? relhist[t] : 0;
    s[t] = v; __syncthreads();
    #pragma unroll
    for (int off = 1; off < 32; off <<= 1) {
        int u = (t >= off && t < N_RELS) ? s[t - off] : 0;
        __syncthreads(); s[t] += u; __syncthreads();
    }
    if (t < N_RELS) { int ex = s[t] - v; roff[t] = ex; relcur[t] = ex; }
    if (t == N_RELS - 1) roff[N_RELS] = s[t];
    __syncthreads();
    int w = (v + TILE_M - 1) / TILE_M;
    s[t] = (t < N_RELS) ? w : 0; __syncthreads();
    #pragma unroll
    for (int off = 1; off < 32; off <<= 1) {
        int u = (t >= off && t < N_RELS) ? s[t - off] : 0;
        __syncthreads(); s[t] += u; __syncthreads();
    }
    if (t < N_RELS) tb[t] = s[t] - w;
    if (t == N_RELS - 1) tb[N_RELS] = s[t];
    __syncthreads();
    int v2 = (t < NBKT) ? bkthist[t] : 0;
    s[t] = v2; __syncthreads();
    #pragma unroll
    for (int off = 1; off < 256; off <<= 1) {
        int u = (t >= off) ? s[t - off] : 0;
        __syncthreads(); s[t] += u; __syncthreads();
    }
    if (t < NBKT) { int ex = s[t] - v2; bktoff[t] = ex; bktcur[t] = ex; }
    if (t == NBKT - 1) bktoff[NBKT] = s[t];
    if (t == 0) dst_off[N_NODES] = N_EDGES;
}

// ---------------- kC: rel-scatter + dst-bucket scatter (LDS-aggregated) -----
__global__ __launch_bounds__(256) void kC_scatter(const int* __restrict__ src,
                                                  const int* __restrict__ dst,
                                                  const int* __restrict__ et,
                                                  int* __restrict__ relcur,
                                                  int* __restrict__ bktcur,
                                                  int* __restrict__ relsrc,
                                                  int* __restrict__ bucketed)
{
    __shared__ int lh[N_RELS],  lbase[N_RELS];
    __shared__ int lb[NBKT],    lbase2[NBKT];
    const int t = threadIdx.x;
    if (t < N_RELS) lh[t] = 0;
    if (t < NBKT)   lb[t] = 0;
    __syncthreads();
    const int base = blockIdx.x * EPB + t * 8;
    int r_[8], b_[8], s_[8], d_[8], sl[8], sl2[8];
    #pragma unroll
    for (int i = 0; i < 8; ++i) {
        int e = base + i;
        if (e < N_EDGES) {
            r_[i] = et[e]; s_[i] = src[e]; d_[i] = dst[e];
            b_[i] = d_[i] >> 8;
            sl[i]  = atomicAdd(&lh[r_[i]], 1);
            sl2[i] = atomicAdd(&lb[b_[i]], 1);
        }
    }
    __syncthreads();
    if (t < N_RELS && lh[t]) lbase[t]  = atomicAdd(&relcur[t], lh[t]);
    if (t < NBKT   && lb[t]) lbase2[t] = atomicAdd(&bktcur[t], lb[t]);
    __syncthreads();
    #pragma unroll
    for (int i = 0; i < 8; ++i) {
        int e = base + i;
        if (e < N_EDGES) {
            int j = lbase[r_[i]] + sl[i];
            relsrc[j] = s_[i];
            bucketed[lbase2[b_[i]] + sl2[i]] = ((d_[i] & 255) << 20) | j;
        }
    }
}

// ---------------- kD: per-bucket counting sort -> dst_off + j2pos -----------
__global__ __launch_bounds__(256) void kD_csr(const int* __restrict__ bucketed,
                                              const int* __restrict__ bktoff,
                                              int* __restrict__ j2pos,
                                              int* __restrict__ dst_off)
{
    __shared__ int hist[256];
    __shared__ int s[256];
    const int b = blockIdx.x, t = threadIdx.x;
    const int lo = bktoff[b], hi = bktoff[b + 1];
    hist[t] = 0; __syncthreads();
    for (int p = lo + t; p < hi; p += 256)
        atomicAdd(&hist[bucketed[p] >> 20], 1);
    __syncthreads();
    int v = hist[t];
    s[t] = v; __syncthreads();
    #pragma unroll
    for (int off = 1; off < 256; off <<= 1) {
        int u = (t >= off) ? s[t - off] : 0;
        __syncthreads(); s[t] += u; __syncthreads();
    }
    int ex = lo + s[t] - v;
    int n = b * 256 + t;
    if (n < N_NODES) dst_off[n] = ex;
    hist[t] = ex;
    __syncthreads();
    for (int p = lo + t; p < hi; p += 256) {
        int key = bucketed[p];
        int pos = atomicAdd(&hist[key >> 20], 1);
        j2pos[key & 0xFFFFF] = pos;        // inverse map: rel-index -> dst-CSR slot
    }
}

// ---------------- K4: per-relation GEMM via MFMA -> Y (dst-ordered) ---------
// TILE_M=128, 256 threads (4 waves), LDS 24.5 KB -> 6 blocks/CU.
template <bool USE_H>
__global__ __launch_bounds__(256) void k4_gemm(const float* __restrict__ feat,
                                               const _Float16* __restrict__ featH,
                                               const _Float16* __restrict__ wT,
                                               const int* __restrict__ relsrc,
                                               const int* __restrict__ j2pos,
                                               const int* __restrict__ roff,
                                               const int* __restrict__ tb,
                                               _Float16* __restrict__ Y)
{
    __shared__ _Float16 aT[TILE_M * 64];   // XOR-swizzled [row][k], 16 KB
    __shared__ _Float16 wL[64 * 64];       // XOR-swizzled [out][k],  8 KB
    __shared__ int      ypos[TILE_M];      // dst-CSR slot per tile row
    const int b = blockIdx.x, t = threadIdx.x;

    int r = -1, ti = 0, t0 = 0;
    #pragma unroll
    for (int q = 0; q < N_RELS; ++q) {
        int t1 = tb[q + 1];
        if (b >= t0 && b < t1) { r = q; ti = b - t0; }
        t0 = t1;
    }
    if (r < 0) return;
    const int segend  = roff[r + 1];
    const int rowbase = roff[r] + ti * TILE_M;

    if (t < TILE_M) {
        // threads 0-127: stage one A row + its output position
        const int j = rowbase + t;
        const bool ok = (j < segend);
        const int sidx = ok ? relsrc[j] : 0;
        ypos[t] = ok ? j2pos[j] : 0;
        if (USE_H) {
            const half8* hrow = reinterpret_cast<const half8*>(featH + (size_t)sidx * 64);
            #pragma unroll
            for (int c = 0; c < 4; ++c) {
                half8 h0 = hrow[c * 2 + 0];
                half8 h1 = hrow[c * 2 + 1];
                int base = t * 128 + c * 32;
                int a0 = (base)      ^ ((t & 7) << 4);
                int a1 = (base + 16) ^ ((t & 7) << 4);
                *reinterpret_cast<half8*>(reinterpret_cast<char*>(aT) + a0) = h0;
                *reinterpret_cast<half8*>(reinterpret_cast<char*>(aT) + a1) = h1;
            }
        } else {
            const float4* frow = reinterpret_cast<const float4*>(feat + (size_t)sidx * 64);
            #pragma unroll
            for (int c = 0; c < 4; ++c) {
                float4 f0 = frow[c*4+0], f1 = frow[c*4+1], f2 = frow[c*4+2], f3 = frow[c*4+3];
                half8 h0, h1;
                h0[0]=(_Float16)f0.x; h0[1]=(_Float16)f0.y; h0[2]=(_Float16)f0.z; h0[3]=(_Float16)f0.w;
                h0[4]=(_Float16)f1.x; h0[5]=(_Float16)f1.y; h0[6]=(_Float16)f1.z; h0[7]=(_Float16)f1.w;
                h1[0]=(_Float16)f2.x; h1[1]=(_Float16)f2.y; h1[2]=(_Float16)f2.z; h1[3]=(_Float16)f2.w;
                h1[4]=(_Float16)f3.x; h1[5]=(_Float16)f3.y; h1[6]=(_Float16)f3.z; h1[7]=(_Float16)f3.w;
                int base = t * 128 + c * 32;
                int a0 = (base)      ^ ((t & 7) << 4);
                int a1 = (base + 16) ^ ((t & 7) << 4);
                *reinterpret_cast<half8*>(reinterpret_cast<char*>(aT) + a0) = h0;
                *reinterpret_cast<half8*>(reinterpret_cast<char*>(aT) + a1) = h1;
            }
        }
    } else {
        // threads 128-255: stage W^T (4 x half8 each)
        const _Float16* wsrc = wT + (size_t)r * 4096;
        const int tt = t - 128;
        #pragma unroll
        for (int it = 0; it < 4; ++it) {
            int L8 = it * 128 + tt;
            int o = L8 >> 3, kcol = (L8 & 7) * 8;
            int baddr = (o * 128 + kcol * 2) ^ ((o & 7) << 4);
            *reinterpret_cast<half8*>(reinterpret_cast<char*>(wL) + baddr) =
                *reinterpret_cast<const half8*>(wsrc + L8 * 8);
        }
    }
    __syncthreads();

    const int wid = t >> 6, l = t & 63;
    const int lrow = l & 15, lkb = l >> 4;
    f32x4 acc[2][4] = {};
    #pragma unroll
    for (int ks = 0; ks < 2; ++ks) {
        half8 af[2], bfr[4];
        #pragma unroll
        for (int rt = 0; rt < 2; ++rt) {
            int row = wid * 32 + rt * 16 + lrow;
            int baddr = (row * 128 + ks * 64 + lkb * 16) ^ ((row & 7) << 4);
            af[rt] = *reinterpret_cast<const half8*>(reinterpret_cast<const char*>(aT) + baddr);
        }
        #pragma unroll
        for (int ct = 0; ct < 4; ++ct) {
            int n = ct * 16 + lrow;
            int baddr = (n * 128 + ks * 64 + lkb * 16) ^ ((n & 7) << 4);
            bfr[ct] = *reinterpret_cast<const half8*>(reinterpret_cast<const char*>(wL) + baddr);
        }
        #pragma unroll
        for (int rt = 0; rt < 2; ++rt)
            #pragma unroll
            for (int ct = 0; ct < 4; ++ct)
                acc[rt][ct] = __builtin_amdgcn_mfma_f32_16x16x32_f16(af[rt], bfr[ct], acc[rt][ct], 0, 0, 0);
    }
    // scatter each output row to its dst-CSR slot
    #pragma unroll
    for (int rt = 0; rt < 2; ++rt) {
        int lrow0 = wid * 32 + rt * 16 + (l >> 4) * 4;
        #pragma unroll
        for (int reg = 0; reg < 4; ++reg) {
            int lr = lrow0 + reg;
            if (rowbase + lr < segend) {
                size_t yrow = (size_t)ypos[lr] * 64;
                #pragma unroll
                for (int ct = 0; ct < 4; ++ct)
                    Y[yrow + ct * 16 + lrow] = (_Float16)acc[rt][ct][reg];
            }
        }
    }
}

// ---------------- K5: streaming reduce over dst-ordered Y ----------------
__global__ __launch_bounds__(256) void k5_reduce(const _Float16* __restrict__ Y,
                                                 const int* __restrict__ dst_off,
                                                 float* __restrict__ out)
{
    const int wid = threadIdx.x >> 6, l = threadIdx.x & 63;
    const int n = blockIdx.x * 4 + wid;
    if (n >= N_NODES) return;
    const int p0 = dst_off[n], p1 = dst_off[n + 1];
    float acc = 0.f;
    int p = p0;
    for (; p + 4 <= p1; p += 4) {
        acc += (float)Y[(size_t)(p+0) * 64 + l] + (float)Y[(size_t)(p+1) * 64 + l]
             + (float)Y[(size_t)(p+2) * 64 + l] + (float)Y[(size_t)(p+3) * 64 + l];
    }
    for (; p < p1; ++p)
        acc += (float)Y[(size_t)p * 64 + l];
    out[(size_t)n * 64 + l] = acc;
}

extern "C" void kernel_launch(void* const* d_in, const int* in_sizes, int n_in,
                              void* d_out, int out_size, void* d_ws, size_t ws_size,
                              hipStream_t stream) {
    const float* feat   = (const float*)d_in[0];
    const float* weight = (const float*)d_in[1];
    const int*   src    = (const int*)d_in[2];
    const int*   dst    = (const int*)d_in[3];
    const int*   et     = (const int*)d_in[4];
    float*       out    = (float*)d_out;

    if (ws_size < (size_t)WS_BASE) {
        hipMemsetAsync(d_out, 0, (size_t)out_size * sizeof(float), stream);
        hipLaunchKernelGGL(rgcn_edge_atomic, dim3(4096), dim3(256), 0, stream,
                           feat, weight, src, dst, et, out, N_EDGES / 4);
        return;
    }
    const bool use_h = (ws_size >= (size_t)WS_FULL);

    char* ws = (char*)d_ws;
    int*       relhist  = (int*)(ws + OFF_RELHIST);
    int*       bkthist  = (int*)(ws + OFF_BKTHIST);
    int*       relcur   = (int*)(ws + OFF_RELCUR);
    int*       bktcur   = (int*)(ws + OFF_BKTCUR);
    int*       roff     = (int*)(ws + OFF_ROFF);
    int*       tb       = (int*)(ws + OFF_TB);
    int*       bktoff   = (int*)(ws + OFF_BKTOFF);
    int*       dst_off  = (int*)(ws + OFF_DSTOFF);
    int*       relsrc   = (int*)(ws + OFF_RELSRC);
    int*       j2pos    = (int*)(ws + OFF_J2POS);
    _Float16*  wT       = (_Float16*)(ws + OFF_WT);
    _Float16*  featH    = (_Float16*)(ws + OFF_FEATH);
    _Float16*  Y        = (_Float16*)(ws + (use_h ? OFF_Y_FULL : OFF_Y_BASE));
    int*       bucketed = (int*)Y;              // aliases Y head; dead before k4

    hipMemsetAsync(ws, 0, 912, stream);         // relhist + bkthist

    const int pre_blocks = use_h ? (N_RELS + (N_NODES * D / 8 + 255) / 256) : N_RELS;
    hipLaunchKernelGGL(kPre,       dim3(pre_blocks), dim3(256), 0, stream, weight, wT, feat, featH);
    hipLaunchKernelGGL(kA_hist,    dim3(NEBLK),  dim3(256), 0, stream, et, dst, relhist, bkthist);
    hipLaunchKernelGGL(kB_scan,    dim3(1),      dim3(256), 0, stream, relhist, bkthist, roff, relcur, tb, bktoff, bktcur, dst_off);
    hipLaunchKernelGGL(kC_scatter, dim3(NEBLK),  dim3(256), 0, stream, src, dst, et, relcur, bktcur, relsrc, bucketed);
    hipLaunchKernelGGL(kD_csr,     dim3(NBKT),   dim3(256), 0, stream, bucketed, bktoff, j2pos, dst_off);
    const int max_tiles = N_EDGES / TILE_M + N_RELS;   // 6282 upper bound
    if (use_h)
        hipLaunchKernelGGL((k4_gemm<true>),  dim3(max_tiles), dim3(256), 0, stream, feat, featH, wT, relsrc, j2pos, roff, tb, Y);
    else
        hipLaunchKernelGGL((k4_gemm<false>), dim3(max_tiles), dim3(256), 0, stream, feat, featH, wT, relsrc, j2pos, roff, tb, Y);
    hipLaunchKernelGGL(k5_reduce,  dim3((N_NODES + 3) / 4), dim3(256), 0, stream, Y, dst_off, out);
}

// Round 8
// 114.396 us; speedup vs baseline: 2.3088x; 1.0442x over previous
//
#include <hip/hip_runtime.h>
#include <hip/hip_bf16.h>

#define N_NODES 50000
#define N_EDGES 800000
#define N_RELS  32
#define D       64
#define TILE_M  128
#define NBKT    196                         // ceil(50000/256)
#define EPB     2048                        // edges per block in kA/kC
#define NEBLK   ((N_EDGES + EPB - 1) / EPB) // 391

typedef _Float16 half8 __attribute__((ext_vector_type(8)));
typedef float    f32x4 __attribute__((ext_vector_type(4)));

// ---------------- workspace layout (bytes) ----------------
#define OFF_RELHIST 0u          // 32 int
#define OFF_BKTHIST 128u        // 196 int   (zeroed by kPre block 0)
#define OFF_RELCUR  1024u       // 32 int
#define OFF_BKTCUR  1152u       // 196 int
#define OFF_ROFF    1936u       // 33 int
#define OFF_TB      2080u       // 33 int
#define OFF_BKTOFF  2224u       // 197 int
#define OFF_DSTOFF  3072u       // 50001 int
#define OFF_RELSRC  203776u     // 800000 int
#define OFF_J2POS   3403776u    // 800000 int (edge j -> dst-CSR position)
#define OFF_WT      6603776u    // 32*64*64 fp16
#define OFF_FEATH   6865920u    // 50000*64 fp16 (full layout only)
#define OFF_Y_FULL  13265920u   // 800000*64 fp16, dst-ordered
#define OFF_Y_BASE  6865920u    // Y location when featH doesn't fit
#define WS_FULL     115665920u
#define WS_BASE     109265920u

// ---------------- fallback: atomic scatter path ----------------
__global__ __launch_bounds__(256) void rgcn_edge_atomic(
    const float* __restrict__ feat, const float* __restrict__ weight,
    const int* __restrict__ src, const int* __restrict__ dst,
    const int* __restrict__ et, float* __restrict__ out, int nquads)
{
    const int tid  = blockIdx.x * blockDim.x + threadIdx.x;
    const int wave = tid >> 6, lane = tid & 63;
    const int grp = lane >> 4, lg = lane & 15;
    const int wave_stride = (gridDim.x * blockDim.x) >> 6;
    for (int q = wave; q < nquads; q += wave_stride) {
        const int e = q * 4 + grp;
        const int s = src[e], d = dst[e], r = et[e];
        const float* w = weight + (size_t)r * D * D + lg * 4;
        float ax = 0.f, ay = 0.f, az = 0.f, aw = 0.f;
        #pragma unroll
        for (int i4 = 0; i4 < D / 4; ++i4) {
            const float4 f  = *reinterpret_cast<const float4*>(feat + (size_t)s * D + i4 * 4);
            const float4 w0 = *reinterpret_cast<const float4*>(w + (i4 * 4 + 0) * D);
            const float4 w1 = *reinterpret_cast<const float4*>(w + (i4 * 4 + 1) * D);
            const float4 w2 = *reinterpret_cast<const float4*>(w + (i4 * 4 + 2) * D);
            const float4 w3 = *reinterpret_cast<const float4*>(w + (i4 * 4 + 3) * D);
            ax += f.x*w0.x; ay += f.x*w0.y; az += f.x*w0.z; aw += f.x*w0.w;
            ax += f.y*w1.x; ay += f.y*w1.y; az += f.y*w1.z; aw += f.y*w1.w;
            ax += f.z*w2.x; ay += f.z*w2.y; az += f.z*w2.z; aw += f.z*w2.w;
            ax += f.w*w3.x; ay += f.w*w3.y; az += f.w*w3.z; aw += f.w*w3.w;
        }
        float* orow = out + (size_t)d * D + lg * 4;
        atomicAdd(orow + 0, ax); atomicAdd(orow + 1, ay);
        atomicAdd(orow + 2, az); atomicAdd(orow + 3, aw);
    }
}

// ---------------- kPre: zero hists + W->W^T fp16 + feat->fp16 (fused) -------
__global__ __launch_bounds__(256) void kPre(const float* __restrict__ w,
                                            _Float16* __restrict__ wT,
                                            const float* __restrict__ feat,
                                            _Float16* __restrict__ featH,
                                            int* __restrict__ histzero)
{
    const int t = threadIdx.x;
    if (blockIdx.x < N_RELS) {
        if (blockIdx.x == 0 && t < 228)     // relhist(32) + bkthist(196)
            histzero[t] = 0;
        const int r = blockIdx.x;
        #pragma unroll
        for (int i = 0; i < 16; ++i) {
            int oidx = i * 256 + t;
            int o = oidx >> 6, k = oidx & 63;
            wT[(size_t)r * 4096 + oidx] = (_Float16)w[(size_t)r * 4096 + k * 64 + o];
        }
    } else {
        const int base = ((blockIdx.x - N_RELS) * 256 + t) * 8;
        if (base >= N_NODES * D) return;
        float4 f0 = *reinterpret_cast<const float4*>(feat + base);
        float4 f1 = *reinterpret_cast<const float4*>(feat + base + 4);
        half8 h;
        h[0]=(_Float16)f0.x; h[1]=(_Float16)f0.y; h[2]=(_Float16)f0.z; h[3]=(_Float16)f0.w;
        h[4]=(_Float16)f1.x; h[5]=(_Float16)f1.y; h[6]=(_Float16)f1.z; h[7]=(_Float16)f1.w;
        *reinterpret_cast<half8*>(featH + base) = h;
    }
}

// ---------------- kA: LDS-aggregated rel + bucket histograms ----------------
__global__ __launch_bounds__(256) void kA_hist(const int* __restrict__ et,
                                               const int* __restrict__ dst,
                                               int* __restrict__ relhist,
                                               int* __restrict__ bkthist)
{
    __shared__ int lh[N_RELS];
    __shared__ int lb[NBKT];
    const int t = threadIdx.x;
    if (t < N_RELS) lh[t] = 0;
    if (t < NBKT)   lb[t] = 0;
    __syncthreads();
    const int base = blockIdx.x * EPB + t * 8;
    #pragma unroll
    for (int i = 0; i < 8; ++i) {
        int e = base + i;
        if (e < N_EDGES) {
            atomicAdd(&lh[et[e]], 1);
            atomicAdd(&lb[dst[e] >> 8], 1);
        }
    }
    __syncthreads();
    if (t < N_RELS && lh[t]) atomicAdd(&relhist[t], lh[t]);
    if (t < NBKT   && lb[t]) atomicAdd(&bkthist[t], lb[t]);
}

// ---------------- kB: parallel scans (rel offsets, tile table, bucket offs) -
__global__ __launch_bounds__(256) void kB_scan(const int* __restrict__ relhist,
                                               const int* __restrict__ bkthist,
                                               int* __restrict__ roff,
                                               int* __restrict__ relcur,
                                               int* __restrict__ tb,
                                               int* __restrict__ bktoff,
                                               int* __restrict__ bktcur,
                                               int* __restrict__ dst_off)
{
    __shared__ int s[256];
    const int t = threadIdx.x;
    int v = (t < N_RELS) ? relhist[t] : 0;
    s[t] = v; __syncthreads();
    #pragma unroll
    for (int off = 1; off < 32; off <<= 1) {
        int u = (t >= off && t < N_RELS) ? s[t - off] : 0;
        __syncthreads(); s[t] += u; __syncthreads();
    }
    if (t < N_RELS) { int ex = s[t] - v; roff[t] = ex; relcur[t] = ex; }
    if (t == N_RELS - 1) roff[N_RELS] = s[t];
    __syncthreads();
    int w = (v + TILE_M - 1) / TILE_M;
    s[t] = (t < N_RELS) ? w : 0; __syncthreads();
    #pragma unroll
    for (int off = 1; off < 32; off <<= 1) {
        int u = (t >= off && t < N_RELS) ? s[t - off] : 0;
        __syncthreads(); s[t] += u; __syncthreads();
    }
    if (t < N_RELS) tb[t] = s[t] - w;
    if (t == N_RELS - 1) tb[N_RELS] = s[t];
    __syncthreads();
    int v2 = (t < NBKT) ? bkthist[t] : 0;
    s[t] = v2; __syncthreads();
    #pragma unroll
    for (int off = 1; off < 256; off <<= 1) {
        int u = (t >= off) ? s[t - off] : 0;
        __syncthreads(); s[t] += u; __syncthreads();
    }
    if (t < NBKT) { int ex = s[t] - v2; bktoff[t] = ex; bktcur[t] = ex; }
    if (t == NBKT - 1) bktoff[NBKT] = s[t];
    if (t == 0) dst_off[N_NODES] = N_EDGES;
}

// ---------------- kC: rel-scatter + dst-bucket scatter (LDS-aggregated) -----
__global__ __launch_bounds__(256) void kC_scatter(const int* __restrict__ src,
                                                  const int* __restrict__ dst,
                                                  const int* __restrict__ et,
                                                  int* __restrict__ relcur,
                                                  int* __restrict__ bktcur,
                                                  int* __restrict__ relsrc,
                                                  int* __restrict__ bucketed)
{
    __shared__ int lh[N_RELS],  lbase[N_RELS];
    __shared__ int lb[NBKT],    lbase2[NBKT];
    const int t = threadIdx.x;
    if (t < N_RELS) lh[t] = 0;
    if (t < NBKT)   lb[t] = 0;
    __syncthreads();
    const int base = blockIdx.x * EPB + t * 8;
    int r_[8], b_[8], s_[8], d_[8], sl[8], sl2[8];
    #pragma unroll
    for (int i = 0; i < 8; ++i) {
        int e = base + i;
        if (e < N_EDGES) {
            r_[i] = et[e]; s_[i] = src[e]; d_[i] = dst[e];
            b_[i] = d_[i] >> 8;
            sl[i]  = atomicAdd(&lh[r_[i]], 1);
            sl2[i] = atomicAdd(&lb[b_[i]], 1);
        }
    }
    __syncthreads();
    if (t < N_RELS && lh[t]) lbase[t]  = atomicAdd(&relcur[t], lh[t]);
    if (t < NBKT   && lb[t]) lbase2[t] = atomicAdd(&bktcur[t], lb[t]);
    __syncthreads();
    #pragma unroll
    for (int i = 0; i < 8; ++i) {
        int e = base + i;
        if (e < N_EDGES) {
            int j = lbase[r_[i]] + sl[i];
            relsrc[j] = s_[i];
            bucketed[lbase2[b_[i]] + sl2[i]] = ((d_[i] & 255) << 20) | j;
        }
    }
}

// ---------------- kD: per-bucket counting sort -> dst_off + j2pos -----------
__global__ __launch_bounds__(256) void kD_csr(const int* __restrict__ bucketed,
                                              const int* __restrict__ bktoff,
                                              int* __restrict__ j2pos,
                                              int* __restrict__ dst_off)
{
    __shared__ int hist[256];
    __shared__ int s[256];
    const int b = blockIdx.x, t = threadIdx.x;
    const int lo = bktoff[b], hi = bktoff[b + 1];
    hist[t] = 0; __syncthreads();
    for (int p = lo + t; p < hi; p += 256)
        atomicAdd(&hist[bucketed[p] >> 20], 1);
    __syncthreads();
    int v = hist[t];
    s[t] = v; __syncthreads();
    #pragma unroll
    for (int off = 1; off < 256; off <<= 1) {
        int u = (t >= off) ? s[t - off] : 0;
        __syncthreads(); s[t] += u; __syncthreads();
    }
    int ex = lo + s[t] - v;
    int n = b * 256 + t;
    if (n < N_NODES) dst_off[n] = ex;
    hist[t] = ex;
    __syncthreads();
    for (int p = lo + t; p < hi; p += 256) {
        int key = bucketed[p];
        int pos = atomicAdd(&hist[key >> 20], 1);
        j2pos[key & 0xFFFFF] = pos;        // inverse map: rel-index -> dst-CSR slot
    }
}

// ---------------- K4: per-relation GEMM via MFMA -> Y (dst-ordered) ---------
// TILE_M=128, 256 threads (4 waves), LDS ~25 KB -> 6 blocks/CU.
template <bool USE_H>
__global__ __launch_bounds__(256) void k4_gemm(const float* __restrict__ feat,
                                               const _Float16* __restrict__ featH,
                                               const _Float16* __restrict__ wT,
                                               const int* __restrict__ relsrc,
                                               const int* __restrict__ j2pos,
                                               const int* __restrict__ roff,
                                               const int* __restrict__ tb,
                                               _Float16* __restrict__ Y)
{
    __shared__ _Float16 aT[TILE_M * 64];   // XOR-swizzled [row][k], 16 KB
    __shared__ _Float16 wL[64 * 64];       // XOR-swizzled [out][k],  8 KB
    __shared__ int      ypos[TILE_M];      // dst-CSR slot per tile row
    const int b = blockIdx.x, t = threadIdx.x;

    int r = -1, ti = 0, t0 = 0;
    #pragma unroll
    for (int q = 0; q < N_RELS; ++q) {
        int t1 = tb[q + 1];
        if (b >= t0 && b < t1) { r = q; ti = b - t0; }
        t0 = t1;
    }
    if (r < 0) return;
    const int segend  = roff[r + 1];
    const int rowbase = roff[r] + ti * TILE_M;

    if (t < TILE_M) {
        const int j = rowbase + t;
        const bool ok = (j < segend);
        const int sidx = ok ? relsrc[j] : 0;
        ypos[t] = ok ? j2pos[j] : 0;
        if (USE_H) {
            const half8* hrow = reinterpret_cast<const half8*>(featH + (size_t)sidx * 64);
            #pragma unroll
            for (int c = 0; c < 4; ++c) {
                half8 h0 = hrow[c * 2 + 0];
                half8 h1 = hrow[c * 2 + 1];
                int base = t * 128 + c * 32;
                int a0 = (base)      ^ ((t & 7) << 4);
                int a1 = (base + 16) ^ ((t & 7) << 4);
                *reinterpret_cast<half8*>(reinterpret_cast<char*>(aT) + a0) = h0;
                *reinterpret_cast<half8*>(reinterpret_cast<char*>(aT) + a1) = h1;
            }
        } else {
            const float4* frow = reinterpret_cast<const float4*>(feat + (size_t)sidx * 64);
            #pragma unroll
            for (int c = 0; c < 4; ++c) {
                float4 f0 = frow[c*4+0], f1 = frow[c*4+1], f2 = frow[c*4+2], f3 = frow[c*4+3];
                half8 h0, h1;
                h0[0]=(_Float16)f0.x; h0[1]=(_Float16)f0.y; h0[2]=(_Float16)f0.z; h0[3]=(_Float16)f0.w;
                h0[4]=(_Float16)f1.x; h0[5]=(_Float16)f1.y; h0[6]=(_Float16)f1.z; h0[7]=(_Float16)f1.w;
                h1[0]=(_Float16)f2.x; h1[1]=(_Float16)f2.y; h1[2]=(_Float16)f2.z; h1[3]=(_Float16)f2.w;
                h1[4]=(_Float16)f3.x; h1[5]=(_Float16)f3.y; h1[6]=(_Float16)f3.z; h1[7]=(_Float16)f3.w;
                int base = t * 128 + c * 32;
                int a0 = (base)      ^ ((t & 7) << 4);
                int a1 = (base + 16) ^ ((t & 7) << 4);
                *reinterpret_cast<half8*>(reinterpret_cast<char*>(aT) + a0) = h0;
                *reinterpret_cast<half8*>(reinterpret_cast<char*>(aT) + a1) = h1;
            }
        }
    } else {
        const _Float16* wsrc = wT + (size_t)r * 4096;
        const int tt = t - 128;
        #pragma unroll
        for (int it = 0; it < 4; ++it) {
            int L8 = it * 128 + tt;
            int o = L8 >> 3, kcol = (L8 & 7) * 8;
            int baddr = (o * 128 + kcol * 2) ^ ((o & 7) << 4);
            *reinterpret_cast<half8*>(reinterpret_cast<char*>(wL) + baddr) =
                *reinterpret_cast<const half8*>(wsrc + L8 * 8);
        }
    }
    __syncthreads();

    const int wid = t >> 6, l = t & 63;
    const int lrow = l & 15, lkb = l >> 4;
    f32x4 acc[2][4] = {};
    #pragma unroll
    for (int ks = 0; ks < 2; ++ks) {
        half8 af[2], bfr[4];
        #pragma unroll
        for (int rt = 0; rt < 2; ++rt) {
            int row = wid * 32 + rt * 16 + lrow;
            int baddr = (row * 128 + ks * 64 + lkb * 16) ^ ((row & 7) << 4);
            af[rt] = *reinterpret_cast<const half8*>(reinterpret_cast<const char*>(aT) + baddr);
        }
        #pragma unroll
        for (int ct = 0; ct < 4; ++ct) {
            int n = ct * 16 + lrow;
            int baddr = (n * 128 + ks * 64 + lkb * 16) ^ ((n & 7) << 4);
            bfr[ct] = *reinterpret_cast<const half8*>(reinterpret_cast<const char*>(wL) + baddr);
        }
        #pragma unroll
        for (int rt = 0; rt < 2; ++rt)
            #pragma unroll
            for (int ct = 0; ct < 4; ++ct)
                acc[rt][ct] = __builtin_amdgcn_mfma_f32_16x16x32_f16(af[rt], bfr[ct], acc[rt][ct], 0, 0, 0);
    }
    #pragma unroll
    for (int rt = 0; rt < 2; ++rt) {
        int lrow0 = wid * 32 + rt * 16 + (l >> 4) * 4;
        #pragma unroll
        for (int reg = 0; reg < 4; ++reg) {
            int lr = lrow0 + reg;
            if (rowbase + lr < segend) {
                size_t yrow = (size_t)ypos[lr] * 64;
                #pragma unroll
                for (int ct = 0; ct < 4; ++ct)
                    Y[yrow + ct * 16 + lrow] = (_Float16)acc[rt][ct][reg];
            }
        }
    }
}

// ---------------- K5: streaming reduce over dst-ordered Y ----------------
__global__ __launch_bounds__(256) void k5_reduce(const _Float16* __restrict__ Y,
                                                 const int* __restrict__ dst_off,
                                                 float* __restrict__ out)
{
    const int wid = threadIdx.x >> 6, l = threadIdx.x & 63;
    const int n = blockIdx.x * 4 + wid;
    if (n >= N_NODES) return;
    const int p0 = dst_off[n], p1 = dst_off[n + 1];
    float acc = 0.f;
    int p = p0;
    for (; p + 4 <= p1; p += 4) {
        acc += (float)Y[(size_t)(p+0) * 64 + l] + (float)Y[(size_t)(p+1) * 64 + l]
             + (float)Y[(size_t)(p+2) * 64 + l] + (float)Y[(size_t)(p+3) * 64 + l];
    }
    for (; p < p1; ++p)
        acc += (float)Y[(size_t)p * 64 + l];
    out[(size_t)n * 64 + l] = acc;
}

extern "C" void kernel_launch(void* const* d_in, const int* in_sizes, int n_in,
                              void* d_out, int out_size, void* d_ws, size_t ws_size,
                              hipStream_t stream) {
    const float* feat   = (const float*)d_in[0];
    const float* weight = (const float*)d_in[1];
    const int*   src    = (const int*)d_in[2];
    const int*   dst    = (const int*)d_in[3];
    const int*   et     = (const int*)d_in[4];
    float*       out    = (float*)d_out;

    if (ws_size < (size_t)WS_BASE) {
        hipMemsetAsync(d_out, 0, (size_t)out_size * sizeof(float), stream);
        hipLaunchKernelGGL(rgcn_edge_atomic, dim3(4096), dim3(256), 0, stream,
                           feat, weight, src, dst, et, out, N_EDGES / 4);
        return;
    }
    const bool use_h = (ws_size >= (size_t)WS_FULL);

    char* ws = (char*)d_ws;
    int*       relhist  = (int*)(ws + OFF_RELHIST);
    int*       bkthist  = (int*)(ws + OFF_BKTHIST);
    int*       relcur   = (int*)(ws + OFF_RELCUR);
    int*       bktcur   = (int*)(ws + OFF_BKTCUR);
    int*       roff     = (int*)(ws + OFF_ROFF);
    int*       tb       = (int*)(ws + OFF_TB);
    int*       bktoff   = (int*)(ws + OFF_BKTOFF);
    int*       dst_off  = (int*)(ws + OFF_DSTOFF);
    int*       relsrc   = (int*)(ws + OFF_RELSRC);
    int*       j2pos    = (int*)(ws + OFF_J2POS);
    _Float16*  wT       = (_Float16*)(ws + OFF_WT);
    _Float16*  featH    = (_Float16*)(ws + OFF_FEATH);
    _Float16*  Y        = (_Float16*)(ws + (use_h ? OFF_Y_FULL : OFF_Y_BASE));
    int*       bucketed = (int*)Y;              // aliases Y head; dead before k4

    const int pre_blocks = use_h ? (N_RELS + (N_NODES * D / 8 + 255) / 256) : N_RELS;
    hipLaunchKernelGGL(kPre,       dim3(pre_blocks), dim3(256), 0, stream, weight, wT, feat, featH, (int*)ws);
    hipLaunchKernelGGL(kA_hist,    dim3(NEBLK),  dim3(256), 0, stream, et, dst, relhist, bkthist);
    hipLaunchKernelGGL(kB_scan,    dim3(1),      dim3(256), 0, stream, relhist, bkthist, roff, relcur, tb, bktoff, bktcur, dst_off);
    hipLaunchKernelGGL(kC_scatter, dim3(NEBLK),  dim3(256), 0, stream, src, dst, et, relcur, bktcur, relsrc, bucketed);
    hipLaunchKernelGGL(kD_csr,     dim3(NBKT),   dim3(256), 0, stream, bucketed, bktoff, j2pos, dst_off);
    const int max_tiles = N_EDGES / TILE_M + N_RELS;   // 6282 upper bound
    if (use_h)
        hipLaunchKernelGGL((k4_gemm<true>),  dim3(max_tiles), dim3(256), 0, stream, feat, featH, wT, relsrc, j2pos, roff, tb, Y);
    else
        hipLaunchKernelGGL((k4_gemm<false>), dim3(max_tiles), dim3(256), 0, stream, feat, featH, wT, relsrc, j2pos, roff, tb, Y);
    hipLaunchKernelGGL(k5_reduce,  dim3((N_NODES + 3) / 4), dim3(256), 0, stream, Y, dst_off, out);
}